// Round 7
// baseline (653.775 us; speedup 1.0000x reference)
//
#include <hip/hip_runtime.h>
#include <math.h>

// ---------------------------------------------------------------------------
// UKF(2048) == linear Kalman update (affine model => sigma machinery collapses).
// With C = I + D (||D||~0.02):
//   xp = A x + B u + c1 ; Pk = P + Q (fp32 Pf)
//   T  = Pk + D Pk ; Py = T + T D^T + R ; G = T^T
//   X ~= Py^{-1}: X1 = a(2I - a Py) analytic, then 3 hi-only NS GEMM iters
//   H = G X ; P_out = Pk - H G^T
//   z = Py^{-1} r via X-precond refinement (matvecs) ; x_out = xp + G z
// GEMM: TN MFMA ( TN(A,B)[m][n] = sum_k A[m][k]*B[n][k] ),
// BM=128 x BN=256 block tile, 8 waves of 64x64 (AI = 32 FLOP/LDS-byte, 1.5x
// round-6's 64x32), BK=64, XOR-swizzled LDS (pre-swizzled global source),
// DEPTH-3 prefetch (3 x 48 KB buffers = 144 KB LDS), counted s_waitcnt
// vmcnt(12) + raw s_barrier (loads get ~2 tile-periods to land).
// ---------------------------------------------------------------------------

typedef unsigned short u16;
typedef unsigned int u32;
typedef __attribute__((ext_vector_type(8))) short bf16x8;
typedef __attribute__((ext_vector_type(4))) float f32x4;

#define GN 2048
#define NNE ((size_t)GN * (size_t)GN)

#define WAITVM(N) asm volatile("s_waitcnt vmcnt(" #N ")" ::: "memory")
#define WAITLG()  asm volatile("s_waitcnt lgkmcnt(0)" ::: "memory")
#define BAR()     __builtin_amdgcn_s_barrier()

__device__ __forceinline__ u16 f2bf(float f) {
    union { float f; u32 u; } x; x.f = f;
    u32 r = x.u + 0x7fffu + ((x.u >> 16) & 1u);   // RNE
    return (u16)(r >> 16);
}
__device__ __forceinline__ float bf2f(u16 b) {
    union { u32 u; float f; } x; x.u = ((u32)b) << 16;
    return x.f;
}

__device__ __forceinline__ void gload16(const u16* g, u16* l) {
    __builtin_amdgcn_global_load_lds((const __attribute__((address_space(1))) u32*)g,
                                     (__attribute__((address_space(3))) u32*)l, 16, 0, 0);
}

// ---------------- elementwise / conversion ----------------

// Pf = P + Q (fp32), Pkh = bf16 hi of Pf
__global__ void fuse_pk(const float* __restrict__ P, const float* __restrict__ Q,
                        float* __restrict__ Pf, u16* __restrict__ Ph)
{
    size_t i = (size_t)blockIdx.x * 256 + threadIdx.x;   // over NNE/4
    float4 p = ((const float4*)P)[i];
    float4 q = ((const float4*)Q)[i];
    float s[4] = {p.x + q.x, p.y + q.y, p.z + q.z, p.w + q.w};
    ((float4*)Pf)[i] = make_float4(s[0], s[1], s[2], s[3]);
    ushort4 h;
    u16* hp = (u16*)&h;
#pragma unroll
    for (int e = 0; e < 4; ++e) hp[e] = f2bf(s[e]);
    ((ushort4*)Ph)[i] = h;
}

// Dh = bf16(C - I)
__global__ void conv_delta(const float* __restrict__ C, u16* __restrict__ Dh)
{
    size_t i = (size_t)blockIdx.x * 256 + threadIdx.x;   // over NNE/4
    size_t base = i * 4;
    u32 row = (u32)(base >> 11);
    u32 col0 = (u32)(base & (GN - 1));
    float4 p = ((const float4*)C)[i];
    float s[4] = {p.x, p.y, p.z, p.w};
    ushort4 h;
    u16* hp = (u16*)&h;
#pragma unroll
    for (int e = 0; e < 4; ++e)
        hp[e] = f2bf(s[e] - ((row == col0 + e) ? 1.0f : 0.0f));
    ((ushort4*)Dh)[i] = h;
}

__global__ void transpose_pair(const u16* __restrict__ Sh, const u16* __restrict__ Sl,
                               u16* __restrict__ Dh, u16* __restrict__ Dl)
{
    __shared__ u16 th[32][33];
    __shared__ u16 tl[32][33];
    int bi = blockIdx.y * 32, bj = blockIdx.x * 32;
    int r = threadIdx.x >> 5, c = threadIdx.x & 31;
    for (int rr = r; rr < 32; rr += 8) {
        th[rr][c] = Sh[(size_t)(bi + rr) * GN + bj + c];
        tl[rr][c] = Sl[(size_t)(bi + rr) * GN + bj + c];
    }
    __syncthreads();
    for (int rr = r; rr < 32; rr += 8) {
        Dh[(size_t)(bj + rr) * GN + bi + c] = th[c][rr];
        Dl[(size_t)(bj + rr) * GN + bi + c] = tl[c][rr];
    }
}

// X1 = a*(2I - a*Py) : first Newton-Schulz step is elementwise for X0 = a*I
__global__ void ns_init(const u16* __restrict__ Pyh, const u16* __restrict__ Pyl,
                        const float* __restrict__ alphap, u16* __restrict__ X)
{
    float a = alphap[0];
    size_t i4 = (size_t)blockIdx.x * 256 + threadIdx.x;   // over NNE/4
    size_t base = i4 * 4;
    u32 row = (u32)(base >> 11);
    u32 col0 = (u32)(base & (GN - 1));
    ushort4 h = ((const ushort4*)Pyh)[i4];
    ushort4 lo = ((const ushort4*)Pyl)[i4];
    u16 hv[4] = {h.x, h.y, h.z, h.w};
    u16 lv[4] = {lo.x, lo.y, lo.z, lo.w};
    ushort4 o;
    u16* op = (u16*)&o;
#pragma unroll
    for (int e = 0; e < 4; ++e) {
        float py = bf2f(hv[e]) + bf2f(lv[e]);
        float v = a * (((row == col0 + e) ? 2.0f : 0.0f) - a * py);
        op[e] = f2bf(v);
    }
    ((ushort4*)X)[i4] = o;
}

// ---------------- vector kernels ----------------

// out[row] = addv[row] + sign*( dot(A[row,:],v1) + dot(B[row,:],v2) )
__global__ void matvec_dual_f32(const float* __restrict__ A, const float* __restrict__ v1,
                                const float* __restrict__ B, const float* __restrict__ v2,
                                const float* __restrict__ addv, float* __restrict__ out,
                                float sign, int n)
{
    int wid = threadIdx.x >> 6, lane = threadIdx.x & 63;
    int row = blockIdx.x * 4 + wid;
    if (row >= n) return;
    const float* ar = A + (size_t)row * n;
    const float* br = B + (size_t)row * n;
    float s = 0.f;
    for (int j = lane; j < n; j += 64) s += ar[j] * v1[j] + br[j] * v2[j];
#pragma unroll
    for (int off = 32; off > 0; off >>= 1) s += __shfl_down(s, off);
    if (lane == 0) out[row] = addv[row] + sign * s;
}

// out[row] = (addv ? addv[row] : 0) + sign * dot((hi+lo)[row,:], v)
__global__ void matvec_hl(const u16* __restrict__ Mh, const u16* __restrict__ Ml,
                          const float* __restrict__ v, const float* __restrict__ addv,
                          float* __restrict__ out, float sign, int n)
{
    int wid = threadIdx.x >> 6, lane = threadIdx.x & 63;
    int row = blockIdx.x * 4 + wid;
    if (row >= n) return;
    const u16* hr = Mh + (size_t)row * n;
    const u16* lr = Ml ? Ml + (size_t)row * n : (const u16*)0;
    float s = 0.f;
    for (int j = lane * 8; j < n; j += 512) {
        uint4 hb = *(const uint4*)&hr[j];
        float4 v0 = *(const float4*)&v[j];
        float4 v1 = *(const float4*)&v[j + 4];
        u32 hw[4] = {hb.x, hb.y, hb.z, hb.w};
        float m[8];
#pragma unroll
        for (int e = 0; e < 4; ++e) {
            m[2 * e]     = bf2f((u16)(hw[e] & 0xffffu));
            m[2 * e + 1] = bf2f((u16)(hw[e] >> 16));
        }
        if (lr) {
            uint4 lb = *(const uint4*)&lr[j];
            u32 lw[4] = {lb.x, lb.y, lb.z, lb.w};
#pragma unroll
            for (int e = 0; e < 4; ++e) {
                m[2 * e]     += bf2f((u16)(lw[e] & 0xffffu));
                m[2 * e + 1] += bf2f((u16)(lw[e] >> 16));
            }
        }
        s += m[0] * v0.x + m[1] * v0.y + m[2] * v0.z + m[3] * v0.w
           + m[4] * v1.x + m[5] * v1.y + m[6] * v1.z + m[7] * v1.w;
    }
#pragma unroll
    for (int off = 32; off > 0; off >>= 1) s += __shfl_down(s, off);
    if (lane == 0) out[row] = (addv ? addv[row] : 0.f) + sign * s;
}

__global__ void vec_sub(const float* __restrict__ a, const float* __restrict__ b,
                        float* __restrict__ o, int n)
{
    int i = blockIdx.x * 256 + threadIdx.x;
    if (i < n) o[i] = a[i] - b[i];
}

__global__ void vec_fill(float* __restrict__ o, float val, int n)
{
    int i = blockIdx.x * 256 + threadIdx.x;
    if (i < n) o[i] = val;
}

__global__ void normsq(const float* __restrict__ v, float* __restrict__ out, int n)
{
    __shared__ float sm[256];
    float s = 0.f;
    for (int i = threadIdx.x; i < n; i += 256) { float x = v[i]; s += x * x; }
    sm[threadIdx.x] = s;
    __syncthreads();
    for (int w = 128; w > 0; w >>= 1) {
        if (threadIdx.x < w) sm[threadIdx.x] += sm[threadIdx.x + w];
        __syncthreads();
    }
    if (threadIdx.x == 0) out[0] = sm[0];
}

__global__ void alpha_k(const float* __restrict__ ns9, const float* __restrict__ ns10,
                        float* __restrict__ alpha)
{
    float lam = sqrtf(ns10[0] / ns9[0]);
    alpha[0] = 2.0f / (1.3f * lam);
}

// -------- MFMA TN-GEMM: BM128 x BN256, 8 waves of 64x64, DEPTH-3 -----------
// O = op(MODE){ sum_s A_s B_s^T } ; MODE 0:S 1:S+Dm 2:Dm-S 3:2I-S 4:S+Dm+Dm2
template <int MODE, int WHI, int WLO, int WF32>
__global__ __launch_bounds__(512, 2) void mfma_gemm(
    const u16* A0, const u16* B0, const u16* A1, const u16* B1, int nseg,
    const float* Dm, const float* Dm2, float* Of, u16* Ohi, u16* Olo)
{
    __shared__ __align__(16) u16 As0[128 * 64];
    __shared__ __align__(16) u16 As1[128 * 64];
    __shared__ __align__(16) u16 As2[128 * 64];
    __shared__ __align__(16) u16 Bs0[256 * 64];
    __shared__ __align__(16) u16 Bs1[256 * 64];
    __shared__ __align__(16) u16 Bs2[256 * 64];
    const int t = threadIdx.x;
    const int wid = t >> 6, l = t & 63;
    const int wr = wid >> 2, wc = wid & 3;            // 2x4 waves, tile 64x64
    const int m0 = blockIdx.y * 128, n0 = blockIdx.x * 256;

    f32x4 acc[4][4] = {};

    // staging: per wave 6 gload16: A rows [wid*16,wid*16+16), B rows
    // [wid*32,wid*32+32). Each gload covers 8 rows (lane>>3) x 8 slots
    // (lane&7). LDS linear; swizzle via permuted GLOBAL source column:
    // phys slot(row, sl) holds global col sl^(row&7); row&7 == l>>3.
    const int srow = l >> 3;                            // 0..7
    const int scol = (((l & 7) ^ srow) << 3);           // source col (elems)
    const size_t ago = (size_t)(m0 + wid * 16 + srow) * GN + scol;
    const size_t bgo = (size_t)(n0 + wid * 32 + srow) * GN + scol;
    const int aldsW = wid * 1024;                       // 16 rows * 64
    const int bldsW = wid * 2048;                       // 32 rows * 64

    // read side: logical k-slot (ks*4 + l>>4) XOR (row&7)
    const int lrow = l & 15;
    const int lq = l >> 4;
    const int lb = l & 7;
    int aoff[4][2], boff[4][2];
#pragma unroll
    for (int mi = 0; mi < 4; ++mi) {
        int r = wr * 64 + mi * 16 + lrow;
#pragma unroll
        for (int ks = 0; ks < 2; ++ks)
            aoff[mi][ks] = r * 64 + (((ks * 4 + lq) ^ lb) << 3);
    }
#pragma unroll
    for (int ni = 0; ni < 4; ++ni) {
        int r = wc * 64 + ni * 16 + lrow;
#pragma unroll
        for (int ks = 0; ks < 2; ++ks)
            boff[ni][ks] = r * 64 + (((ks * 4 + lq) ^ lb) << 3);
    }

    const int nt = nseg * 32;   // BK=64 -> 32 tiles/segment; nt in {32,64}

    auto stage = [&](int tile, u16* Ad, u16* Bd) {   // 6 global_load_lds/wave
        int sn = tile >> 5;
        size_t kn = (size_t)(tile & 31) << 6;
        const u16* Ap = (sn == 0) ? A0 : A1;
        const u16* Bp = (sn == 0) ? B0 : B1;
        const u16* gA = Ap + ago + kn;
        const u16* gB = Bp + bgo + kn;
        gload16(gA,                    Ad + aldsW);
        gload16(gA + (size_t)8  * GN,  Ad + aldsW + 512);
        gload16(gB,                    Bd + bldsW);
        gload16(gB + (size_t)8  * GN,  Bd + bldsW + 512);
        gload16(gB + (size_t)16 * GN,  Bd + bldsW + 1024);
        gload16(gB + (size_t)24 * GN,  Bd + bldsW + 1536);
    };
    auto compute = [&](const u16* Asrc, const u16* Bsrc) {
        __builtin_amdgcn_s_setprio(1);
#pragma unroll
        for (int ks = 0; ks < 2; ++ks) {
            bf16x8 af[4], bq[4];
#pragma unroll
            for (int mi = 0; mi < 4; ++mi)
                af[mi] = *(const bf16x8*)&Asrc[aoff[mi][ks]];
#pragma unroll
            for (int ni = 0; ni < 4; ++ni)
                bq[ni] = *(const bf16x8*)&Bsrc[boff[ni][ks]];
#pragma unroll
            for (int mi = 0; mi < 4; ++mi)
#pragma unroll
                for (int ni = 0; ni < 4; ++ni)
                    acc[mi][ni] = __builtin_amdgcn_mfma_f32_16x16x32_bf16(
                        af[mi], bq[ni], acc[mi][ni], 0, 0, 0);
        }
        __builtin_amdgcn_s_setprio(0);
    };

    // ---- depth-3 pipeline: counted vmcnt, invariant 18 loads in flight ----
    stage(0, As0, Bs0);
    stage(1, As1, Bs1);
    stage(2, As2, Bs2);                     // 18 in flight
    for (int tt = 0; tt < nt - 3; ++tt) {
        switch (tt % 3) {
        case 0:
            WAITVM(12); BAR(); compute(As0, Bs0);
            WAITLG();   BAR(); stage(tt + 3, As0, Bs0);
            break;
        case 1:
            WAITVM(12); BAR(); compute(As1, Bs1);
            WAITLG();   BAR(); stage(tt + 3, As1, Bs1);
            break;
        default:
            WAITVM(12); BAR(); compute(As2, Bs2);
            WAITLG();   BAR(); stage(tt + 3, As2, Bs2);
            break;
        }
    }
    // tail: tiles nt-3, nt-2, nt-1 staged; counted drain 12/6/0
    switch ((nt - 3) % 3) {
    case 0:
        WAITVM(12); BAR(); compute(As0, Bs0);
        WAITVM(6);  BAR(); compute(As1, Bs1);
        WAITVM(0);  BAR(); compute(As2, Bs2);
        break;
    case 1:
        WAITVM(12); BAR(); compute(As1, Bs1);
        WAITVM(6);  BAR(); compute(As2, Bs2);
        WAITVM(0);  BAR(); compute(As0, Bs0);
        break;
    default:
        WAITVM(12); BAR(); compute(As2, Bs2);
        WAITVM(6);  BAR(); compute(As0, Bs0);
        WAITVM(0);  BAR(); compute(As1, Bs1);
        break;
    }

    // epilogue: C/D frag mapping col = l&15, row = (l>>4)*4 + r
#pragma unroll
    for (int mi = 0; mi < 4; ++mi) {
#pragma unroll
        for (int r = 0; r < 4; ++r) {
            int gm = m0 + wr * 64 + mi * 16 + lq * 4 + r;
            size_t rowo = (size_t)gm * GN;
#pragma unroll
            for (int ni = 0; ni < 4; ++ni) {
                int gn = n0 + wc * 64 + ni * 16 + lrow;
                float v = acc[mi][ni][r];
                if (MODE == 1) v = v + Dm[rowo + gn];
                else if (MODE == 2) v = Dm[rowo + gn] - v;
                else if (MODE == 3) v = ((gm == gn) ? 2.0f : 0.0f) - v;
                else if (MODE == 4) v = v + Dm[rowo + gn] + Dm2[rowo + gn];
                if (WF32) Of[rowo + gn] = v;
                if (WHI) {
                    u16 h = f2bf(v);
                    Ohi[rowo + gn] = h;
                    if (WLO) Olo[rowo + gn] = f2bf(v - bf2f(h));
                }
            }
        }
    }
}

// ---------------- host ----------------

extern "C" void kernel_launch(void* const* d_in, const int* in_sizes, int n_in,
                              void* d_out, int out_size, void* d_ws, size_t ws_size,
                              hipStream_t stream)
{
    const int n = GN;
    const float* x  = (const float*)d_in[0];
    const float* y  = (const float*)d_in[1];
    const float* u  = (const float*)d_in[2];
    const float* P  = (const float*)d_in[3];
    const float* Q  = (const float*)d_in[4];
    const float* R  = (const float*)d_in[5];
    const float* A  = (const float*)d_in[6];
    const float* B  = (const float*)d_in[7];
    const float* C  = (const float*)d_in[8];
    const float* D  = (const float*)d_in[9];
    const float* c1 = (const float*)d_in[10];
    const float* c2 = (const float*)d_in[11];

    float* out  = (float*)d_out;
    float* xout = out;          // n
    float* Pf   = out + n;      // n*n fp32: Pk, becomes P_out in place

    // 8 bf16 NxN slots + Tf fp32 (2 slots) + small fp32 vectors  (~84 MB)
    u16* wsu = (u16*)d_ws;
    u16* S0 = wsu + 0 * NNE;  // Delta_h -> E_h
    u16* S1 = wsu + 1 * NNE;  // Pk_h    -> X (odd)  [final X]
    u16* S2 = wsu + 2 * NNE;  // T_h     -> X (even) -> H_l
    u16* S3 = wsu + 3 * NNE;  // T_l     -> H_h
    u16* S4 = wsu + 4 * NNE;  // G_h
    u16* S5 = wsu + 5 * NNE;  // G_l
    u16* S6 = wsu + 6 * NNE;  // Py_h
    u16* S7 = wsu + 7 * NNE;  // Py_l
    float* Tf = (float*)(wsu + 8 * NNE);   // fp32 T (slots 8-9)
    float* vecs = (float*)(wsu + 10 * NNE);
    float* w2   = vecs + 0 * n;
    float* xp   = vecs + 1 * n;
    float* rr   = vecs + 2 * n;
    float* va   = vecs + 3 * n;
    float* vb   = vecs + 4 * n;
    float* z0   = vecs + 5 * n;
    float* z1   = vecs + 6 * n;
    float* rho  = vecs + 7 * n;
    float* scal = vecs + 8 * n;

    dim3 blk256(256), blk512(512);
    dim3 gg(8, 16);             // BN=256 (x), BM=128 (y)

    // Pf = P + Q (+ bf16 hi) ; Delta = C - I (bf16 hi)
    fuse_pk<<<4096, blk256, 0, stream>>>(P, Q, Pf, S1);
    conv_delta<<<4096, blk256, 0, stream>>>(C, S0);

    // xp = A x + B u + c1 ; rr = (y - c2) - (C xp + D u)
    matvec_dual_f32<<<512, blk256, 0, stream>>>(A, x, B, u, c1, xp, 1.0f, n);
    vec_sub<<<8, blk256, 0, stream>>>(y, c2, w2, n);
    matvec_dual_f32<<<512, blk256, 0, stream>>>(C, xp, D, u, w2, rr, -1.0f, n);

    // T = Pk + TN(Delta_h, Pk_h)  -> Tf (fp32) + Th(S2)/Tl(S3)
    mfma_gemm<1, 1, 1, 1><<<gg, blk512, 0, stream>>>(S0, S1, nullptr, nullptr, 1,
                                                     Pf, nullptr, Tf, S2, S3);
    // Py = Tf + R + TN(T_h, Delta_h) -> Py_h(S6)/Py_l(S7)
    mfma_gemm<4, 1, 1, 0><<<gg, blk512, 0, stream>>>(S2, S0, nullptr, nullptr, 1,
                                                     Tf, R, nullptr, S6, S7);
    // G = T^T -> S4/S5
    transpose_pair<<<dim3(64, 64), blk256, 0, stream>>>(S2, S3, S4, S5);

    // power iteration for lambda_max(Py) -> alpha = 2/(1.3*lam)
    vec_fill<<<8, blk256, 0, stream>>>(va, 1.0f, n);
    float* pa = va; float* pb = vb;
    for (int i = 0; i < 7; ++i) {
        matvec_hl<<<512, blk256, 0, stream>>>(S6, nullptr, pa, nullptr, pb, 1.0f, n);
        float* tmp = pa; pa = pb; pb = tmp;
    }
    normsq<<<1, blk256, 0, stream>>>(pa, scal + 0, n);
    matvec_hl<<<512, blk256, 0, stream>>>(S6, nullptr, pa, nullptr, pb, 1.0f, n);
    normsq<<<1, blk256, 0, stream>>>(pb, scal + 1, n);
    alpha_k<<<1, 1, 0, stream>>>(scal + 0, scal + 1, scal + 2);

    // X1 = alpha*(2I - alpha*Py), elementwise -> S2 (T_h dead after G/Py)
    ns_init<<<4096, blk256, 0, stream>>>(S6, S7, scal + 2, S2);

    // 3 cheap NS iterations (hi-only): X: S2 -> S1 -> S2 -> S1
    u16* ch = S2; u16* oh = S1;
    for (int it = 0; it < 3; ++it) {
        mfma_gemm<3, 1, 0, 0><<<gg, blk512, 0, stream>>>(ch, S6, nullptr, nullptr, 1,
                                                         nullptr, nullptr, nullptr, S0, nullptr); // E = 2I - X Py
        mfma_gemm<0, 1, 0, 0><<<gg, blk512, 0, stream>>>(S0, ch, nullptr, nullptr, 1,
                                                         nullptr, nullptr, nullptr, oh, nullptr); // Xn = E X
        u16* tmp = ch; ch = oh; oh = tmp;
    }
    // final X = S1 (hi-only)

    // H = TN(G_h, X) + TN(G_l, X) -> H_h(S3)/H_l(S2)
    mfma_gemm<0, 1, 1, 0><<<gg, blk512, 0, stream>>>(S4, S1, S5, S1, 2,
                                                     nullptr, nullptr, nullptr, S3, S2);
    // P_out = Pf - [TN(H_h, G_h) + TN(H_l, G_h)] -> Pf in place
    mfma_gemm<2, 0, 0, 1><<<gg, blk512, 0, stream>>>(S3, S4, S2, S4, 2,
                                                     Pf, nullptr, Pf, nullptr, nullptr);

    // z = Py^{-1} rr by X-preconditioned iterative refinement (3 steps)
    matvec_hl<<<512, blk256, 0, stream>>>(S1, nullptr, rr, nullptr, z0, 1.0f, n);  // z0 = X r
    matvec_hl<<<512, blk256, 0, stream>>>(S6, S7, z0, rr, rho, -1.0f, n);          // rho = r - Py z0
    matvec_hl<<<512, blk256, 0, stream>>>(S1, nullptr, rho, z0, z1, 1.0f, n);      // z1 = z0 + X rho
    matvec_hl<<<512, blk256, 0, stream>>>(S6, S7, z1, rr, rho, -1.0f, n);          // rho = r - Py z1
    matvec_hl<<<512, blk256, 0, stream>>>(S1, nullptr, rho, z1, z0, 1.0f, n);      // z2 = z1 + X rho
    matvec_hl<<<512, blk256, 0, stream>>>(S6, S7, z0, rr, rho, -1.0f, n);          // rho = r - Py z2
    matvec_hl<<<512, blk256, 0, stream>>>(S1, nullptr, rho, z0, z1, 1.0f, n);      // z3 = z2 + X rho
    // x_out = xp + G z3
    matvec_hl<<<512, blk256, 0, stream>>>(S4, S5, z1, xp, xout, 1.0f, n);
}

// Round 8
// 419.002 us; speedup vs baseline: 1.5603x; 1.5603x over previous
//
#include <hip/hip_runtime.h>
#include <math.h>

// ---------------------------------------------------------------------------
// UKF(2048) == linear Kalman update (affine model => sigma machinery collapses).
// With C = I + D (||D||~0.02):
//   xp = A x + B u + c1 ; Pk = P + Q (fp32 Pf)
//   T  = Pk + D Pk ; Py = T + T D^T + R ; G = T^T
//   X ~= Py^{-1}: X1 = a(2I - a Py) analytic, then 3 hi-only NS GEMM iters
//   H = G X ; P_out = Pk - H G^T
//   z = Py^{-1} r via X-precond refinement (matvecs) ; x_out = xp + G z
// GEMM: TN MFMA ( TN(A,B)[m][n] = sum_k A[m][k]*B[n][k] ), 128x128 block,
// 256 blocks (1/CU), BK=64, depth-4 staging w/ counted vmcnt(12) (r6-proven).
// NEW: in-block split-K wave layout - 8 waves = 2x2 spatial (64x64 tiles)
// x 2 K-halves (K=32 each): LDS fragment reads/tile 96KB -> 64KB (AI 21->32)
// while keeping 2 waves/SIMD and the full 256-block grid. Cross-K reduction
// once per block via padded LDS (stride 68 -> 2-way conflicts only).
// ---------------------------------------------------------------------------

typedef unsigned short u16;
typedef unsigned int u32;
typedef __attribute__((ext_vector_type(8))) short bf16x8;
typedef __attribute__((ext_vector_type(4))) float f32x4;

#define GN 2048
#define NNE ((size_t)GN * (size_t)GN)

#define WAITVM(N) asm volatile("s_waitcnt vmcnt(" #N ")" ::: "memory")
#define WAITLG()  asm volatile("s_waitcnt lgkmcnt(0)" ::: "memory")
#define BAR()     __builtin_amdgcn_s_barrier()

__device__ __forceinline__ u16 f2bf(float f) {
    union { float f; u32 u; } x; x.f = f;
    u32 r = x.u + 0x7fffu + ((x.u >> 16) & 1u);   // RNE
    return (u16)(r >> 16);
}
__device__ __forceinline__ float bf2f(u16 b) {
    union { u32 u; float f; } x; x.u = ((u32)b) << 16;
    return x.f;
}

__device__ __forceinline__ void gload16(const u16* g, u16* l) {
    __builtin_amdgcn_global_load_lds((const __attribute__((address_space(1))) u32*)g,
                                     (__attribute__((address_space(3))) u32*)l, 16, 0, 0);
}

// ---------------- elementwise / conversion ----------------

// Pf = P + Q (fp32), Pkh = bf16 hi of Pf
__global__ void fuse_pk(const float* __restrict__ P, const float* __restrict__ Q,
                        float* __restrict__ Pf, u16* __restrict__ Ph)
{
    size_t i = (size_t)blockIdx.x * 256 + threadIdx.x;   // over NNE/4
    float4 p = ((const float4*)P)[i];
    float4 q = ((const float4*)Q)[i];
    float s[4] = {p.x + q.x, p.y + q.y, p.z + q.z, p.w + q.w};
    ((float4*)Pf)[i] = make_float4(s[0], s[1], s[2], s[3]);
    ushort4 h;
    u16* hp = (u16*)&h;
#pragma unroll
    for (int e = 0; e < 4; ++e) hp[e] = f2bf(s[e]);
    ((ushort4*)Ph)[i] = h;
}

// Dh = bf16(C - I)
__global__ void conv_delta(const float* __restrict__ C, u16* __restrict__ Dh)
{
    size_t i = (size_t)blockIdx.x * 256 + threadIdx.x;   // over NNE/4
    size_t base = i * 4;
    u32 row = (u32)(base >> 11);
    u32 col0 = (u32)(base & (GN - 1));
    float4 p = ((const float4*)C)[i];
    float s[4] = {p.x, p.y, p.z, p.w};
    ushort4 h;
    u16* hp = (u16*)&h;
#pragma unroll
    for (int e = 0; e < 4; ++e)
        hp[e] = f2bf(s[e] - ((row == col0 + e) ? 1.0f : 0.0f));
    ((ushort4*)Dh)[i] = h;
}

__global__ void transpose_pair(const u16* __restrict__ Sh, const u16* __restrict__ Sl,
                               u16* __restrict__ Dh, u16* __restrict__ Dl)
{
    __shared__ u16 th[32][33];
    __shared__ u16 tl[32][33];
    int bi = blockIdx.y * 32, bj = blockIdx.x * 32;
    int r = threadIdx.x >> 5, c = threadIdx.x & 31;
    for (int rr = r; rr < 32; rr += 8) {
        th[rr][c] = Sh[(size_t)(bi + rr) * GN + bj + c];
        tl[rr][c] = Sl[(size_t)(bi + rr) * GN + bj + c];
    }
    __syncthreads();
    for (int rr = r; rr < 32; rr += 8) {
        Dh[(size_t)(bj + rr) * GN + bi + c] = th[c][rr];
        Dl[(size_t)(bj + rr) * GN + bi + c] = tl[c][rr];
    }
}

// X1 = a*(2I - a*Py) : first Newton-Schulz step is elementwise for X0 = a*I
__global__ void ns_init(const u16* __restrict__ Pyh, const u16* __restrict__ Pyl,
                        const float* __restrict__ alphap, u16* __restrict__ X)
{
    float a = alphap[0];
    size_t i4 = (size_t)blockIdx.x * 256 + threadIdx.x;   // over NNE/4
    size_t base = i4 * 4;
    u32 row = (u32)(base >> 11);
    u32 col0 = (u32)(base & (GN - 1));
    ushort4 h = ((const ushort4*)Pyh)[i4];
    ushort4 lo = ((const ushort4*)Pyl)[i4];
    u16 hv[4] = {h.x, h.y, h.z, h.w};
    u16 lv[4] = {lo.x, lo.y, lo.z, lo.w};
    ushort4 o;
    u16* op = (u16*)&o;
#pragma unroll
    for (int e = 0; e < 4; ++e) {
        float py = bf2f(hv[e]) + bf2f(lv[e]);
        float v = a * (((row == col0 + e) ? 2.0f : 0.0f) - a * py);
        op[e] = f2bf(v);
    }
    ((ushort4*)X)[i4] = o;
}

// ---------------- vector kernels ----------------

// out[row] = addv[row] + sign*( dot(A[row,:],v1) + dot(B[row,:],v2) )
__global__ void matvec_dual_f32(const float* __restrict__ A, const float* __restrict__ v1,
                                const float* __restrict__ B, const float* __restrict__ v2,
                                const float* __restrict__ addv, float* __restrict__ out,
                                float sign, int n)
{
    int wid = threadIdx.x >> 6, lane = threadIdx.x & 63;
    int row = blockIdx.x * 4 + wid;
    if (row >= n) return;
    const float* ar = A + (size_t)row * n;
    const float* br = B + (size_t)row * n;
    float s = 0.f;
    for (int j = lane; j < n; j += 64) s += ar[j] * v1[j] + br[j] * v2[j];
#pragma unroll
    for (int off = 32; off > 0; off >>= 1) s += __shfl_down(s, off);
    if (lane == 0) out[row] = addv[row] + sign * s;
}

// out[row] = (addv ? addv[row] : 0) + sign * dot((hi+lo)[row,:], v)
__global__ void matvec_hl(const u16* __restrict__ Mh, const u16* __restrict__ Ml,
                          const float* __restrict__ v, const float* __restrict__ addv,
                          float* __restrict__ out, float sign, int n)
{
    int wid = threadIdx.x >> 6, lane = threadIdx.x & 63;
    int row = blockIdx.x * 4 + wid;
    if (row >= n) return;
    const u16* hr = Mh + (size_t)row * n;
    const u16* lr = Ml ? Ml + (size_t)row * n : (const u16*)0;
    float s = 0.f;
    for (int j = lane * 8; j < n; j += 512) {
        uint4 hb = *(const uint4*)&hr[j];
        float4 v0 = *(const float4*)&v[j];
        float4 v1 = *(const float4*)&v[j + 4];
        u32 hw[4] = {hb.x, hb.y, hb.z, hb.w};
        float m[8];
#pragma unroll
        for (int e = 0; e < 4; ++e) {
            m[2 * e]     = bf2f((u16)(hw[e] & 0xffffu));
            m[2 * e + 1] = bf2f((u16)(hw[e] >> 16));
        }
        if (lr) {
            uint4 lb = *(const uint4*)&lr[j];
            u32 lw[4] = {lb.x, lb.y, lb.z, lb.w};
#pragma unroll
            for (int e = 0; e < 4; ++e) {
                m[2 * e]     += bf2f((u16)(lw[e] & 0xffffu));
                m[2 * e + 1] += bf2f((u16)(lw[e] >> 16));
            }
        }
        s += m[0] * v0.x + m[1] * v0.y + m[2] * v0.z + m[3] * v0.w
           + m[4] * v1.x + m[5] * v1.y + m[6] * v1.z + m[7] * v1.w;
    }
#pragma unroll
    for (int off = 32; off > 0; off >>= 1) s += __shfl_down(s, off);
    if (lane == 0) out[row] = (addv ? addv[row] : 0.f) + sign * s;
}

__global__ void vec_sub(const float* __restrict__ a, const float* __restrict__ b,
                        float* __restrict__ o, int n)
{
    int i = blockIdx.x * 256 + threadIdx.x;
    if (i < n) o[i] = a[i] - b[i];
}

__global__ void vec_fill(float* __restrict__ o, float val, int n)
{
    int i = blockIdx.x * 256 + threadIdx.x;
    if (i < n) o[i] = val;
}

__global__ void normsq(const float* __restrict__ v, float* __restrict__ out, int n)
{
    __shared__ float sm[256];
    float s = 0.f;
    for (int i = threadIdx.x; i < n; i += 256) { float x = v[i]; s += x * x; }
    sm[threadIdx.x] = s;
    __syncthreads();
    for (int w = 128; w > 0; w >>= 1) {
        if (threadIdx.x < w) sm[threadIdx.x] += sm[threadIdx.x + w];
        __syncthreads();
    }
    if (threadIdx.x == 0) out[0] = sm[0];
}

__global__ void alpha_k(const float* __restrict__ ns9, const float* __restrict__ ns10,
                        float* __restrict__ alpha)
{
    float lam = sqrtf(ns10[0] / ns9[0]);
    alpha[0] = 2.0f / (1.3f * lam);
}

// --- MFMA TN-GEMM: 128x128 block, 8 waves = 2x2 spatial x 2 K-split, depth-4
// O = op(MODE){ sum_s A_s B_s^T } ; MODE 0:S 1:S+Dm 2:Dm-S 3:2I-S 4:S+Dm+Dm2
template <int MODE, int WHI, int WLO, int WF32>
__global__ __launch_bounds__(512, 2) void mfma_gemm(
    const u16* A0, const u16* B0, const u16* A1, const u16* B1, int nseg,
    const float* Dm, const float* Dm2, float* Of, u16* Ohi, u16* Olo)
{
    __shared__ __align__(16) u16 ldsbuf[65536];     // 128 KB: A[4] then B[4]
    u16* As0 = ldsbuf;          u16* Bs0 = ldsbuf + 32768;
    u16* As1 = ldsbuf + 8192;   u16* Bs1 = ldsbuf + 40960;
    u16* As2 = ldsbuf + 16384;  u16* Bs2 = ldsbuf + 49152;
    u16* As3 = ldsbuf + 24576;  u16* Bs3 = ldsbuf + 57344;

    const int t = threadIdx.x;
    const int wid = t >> 6, l = t & 63;
    const int wk = wid >> 2;                // K-half (0: k 0-31, 1: k 32-63)
    const int wr = (wid >> 1) & 1;          // 2x2 spatial grid of 64x64 tiles
    const int wc = wid & 1;
    const int m0 = blockIdx.y * 128, n0 = blockIdx.x * 128;

    f32x4 acc[4][4] = {};

    // staging identical to r6: wave w stages A rows [w*16,w*16+16) and B rows
    // [w*16,w*16+16); 2 gload16 each (8 rows per instr). LDS linear; XOR
    // swizzle via permuted GLOBAL source column (rule #21):
    // phys slot(row, sl) holds global col sl^(row&7); row&7 == l>>3.
    const int srow = l >> 3;                            // 0..7
    const int scol = (((l & 7) ^ srow) << 3);           // source col (elems)
    const size_t ago = (size_t)(m0 + wid * 16 + srow) * GN + scol;
    const size_t bgo = (size_t)(n0 + wid * 16 + srow) * GN + scol;
    const int ldsW = wid * 1024;

    // read side: logical k-slot (wk*4 + l>>4) XOR (row&7); K-half by wk
    const int lrow = l & 15;
    const int lq = l >> 4;
    const int lb = l & 7;
    int aoff[4], boff[4];
#pragma unroll
    for (int mi = 0; mi < 4; ++mi) {
        int r = wr * 64 + mi * 16 + lrow;
        aoff[mi] = r * 64 + (((wk * 4 + lq) ^ lb) << 3);
    }
#pragma unroll
    for (int ni = 0; ni < 4; ++ni) {
        int r = wc * 64 + ni * 16 + lrow;
        boff[ni] = r * 64 + (((wk * 4 + lq) ^ lb) << 3);
    }

    const int nt = nseg * 32;   // BK=64 -> 32 tiles/segment; nt in {32,64}

    auto stage = [&](int tile, u16* Ad, u16* Bd) {   // 4 global_load_lds/wave
        int sn = tile >> 5;
        size_t kn = (size_t)(tile & 31) << 6;
        const u16* Ap = (sn == 0) ? A0 : A1;
        const u16* Bp = (sn == 0) ? B0 : B1;
        const u16* gA = Ap + ago + kn;
        const u16* gB = Bp + bgo + kn;
        gload16(gA, Ad + ldsW);
        gload16(gA + (size_t)8 * GN, Ad + ldsW + 512);
        gload16(gB, Bd + ldsW);
        gload16(gB + (size_t)8 * GN, Bd + ldsW + 512);
    };
    auto compute = [&](const u16* Asrc, const u16* Bsrc) {   // K=32 half
        __builtin_amdgcn_s_setprio(1);
        bf16x8 af[4], bq[4];
#pragma unroll
        for (int mi = 0; mi < 4; ++mi)
            af[mi] = *(const bf16x8*)&Asrc[aoff[mi]];
#pragma unroll
        for (int ni = 0; ni < 4; ++ni)
            bq[ni] = *(const bf16x8*)&Bsrc[boff[ni]];
#pragma unroll
        for (int mi = 0; mi < 4; ++mi)
#pragma unroll
            for (int ni = 0; ni < 4; ++ni)
                acc[mi][ni] = __builtin_amdgcn_mfma_f32_16x16x32_bf16(
                    af[mi], bq[ni], acc[mi][ni], 0, 0, 0);
        __builtin_amdgcn_s_setprio(0);
    };

    // ---- depth-4 pipeline (r6-proven): counted vmcnt, 16 loads in flight ---
    stage(0, As0, Bs0);
    stage(1, As1, Bs1);
    stage(2, As2, Bs2);
    stage(3, As3, Bs3);
    int u = 0;
    for (; u + 8 <= nt; u += 4) {
        WAITVM(12); BAR();
        compute(As0, Bs0);
        WAITLG(); BAR();
        stage(u + 4, As0, Bs0);
        WAITVM(12); BAR();
        compute(As1, Bs1);
        WAITLG(); BAR();
        stage(u + 5, As1, Bs1);
        WAITVM(12); BAR();
        compute(As2, Bs2);
        WAITLG(); BAR();
        stage(u + 6, As2, Bs2);
        WAITVM(12); BAR();
        compute(As3, Bs3);
        WAITLG(); BAR();
        stage(u + 7, As3, Bs3);
    }
    // tail: counted drain 12/8/4/0
    WAITVM(12); BAR();
    compute(As0, Bs0);
    WAITVM(8);  BAR();
    compute(As1, Bs1);
    WAITVM(4);  BAR();
    compute(As2, Bs2);
    WAITVM(0);  BAR();
    compute(As3, Bs3);

    // ---- cross-K reduction: wk=1 waves dump acc to padded LDS, wk=0 add ----
    // region per (wr,wc): 64x68 f32 (stride 68 -> 2-way bank conflicts only)
    float* red = (float*)ldsbuf;
    const int reg = (wr * 2 + wc) * 4352;
    WAITLG(); BAR();                       // all LDS tile reads done; safe reuse
    if (wk == 1) {
#pragma unroll
        for (int mi = 0; mi < 4; ++mi)
#pragma unroll
            for (int ni = 0; ni < 4; ++ni)
#pragma unroll
                for (int r = 0; r < 4; ++r)
                    red[reg + (mi * 16 + lq * 4 + r) * 68 + ni * 16 + lrow] =
                        acc[mi][ni][r];
    }
    WAITLG(); BAR();
    if (wk == 0) {
#pragma unroll
        for (int mi = 0; mi < 4; ++mi)
#pragma unroll
            for (int ni = 0; ni < 4; ++ni)
#pragma unroll
                for (int r = 0; r < 4; ++r)
                    acc[mi][ni][r] +=
                        red[reg + (mi * 16 + lq * 4 + r) * 68 + ni * 16 + lrow];

        // epilogue (wk=0 waves only): C/D frag col = l&15, row = lq*4 + r
#pragma unroll
        for (int mi = 0; mi < 4; ++mi) {
#pragma unroll
            for (int r = 0; r < 4; ++r) {
                int gm = m0 + wr * 64 + mi * 16 + lq * 4 + r;
                size_t rowo = (size_t)gm * GN;
#pragma unroll
                for (int ni = 0; ni < 4; ++ni) {
                    int gn = n0 + wc * 64 + ni * 16 + lrow;
                    float v = acc[mi][ni][r];
                    if (MODE == 1) v = v + Dm[rowo + gn];
                    else if (MODE == 2) v = Dm[rowo + gn] - v;
                    else if (MODE == 3) v = ((gm == gn) ? 2.0f : 0.0f) - v;
                    else if (MODE == 4) v = v + Dm[rowo + gn] + Dm2[rowo + gn];
                    if (WF32) Of[rowo + gn] = v;
                    if (WHI) {
                        u16 h = f2bf(v);
                        Ohi[rowo + gn] = h;
                        if (WLO) Olo[rowo + gn] = f2bf(v - bf2f(h));
                    }
                }
            }
        }
    }
}

// ---------------- host ----------------

extern "C" void kernel_launch(void* const* d_in, const int* in_sizes, int n_in,
                              void* d_out, int out_size, void* d_ws, size_t ws_size,
                              hipStream_t stream)
{
    const int n = GN;
    const float* x  = (const float*)d_in[0];
    const float* y  = (const float*)d_in[1];
    const float* u  = (const float*)d_in[2];
    const float* P  = (const float*)d_in[3];
    const float* Q  = (const float*)d_in[4];
    const float* R  = (const float*)d_in[5];
    const float* A  = (const float*)d_in[6];
    const float* B  = (const float*)d_in[7];
    const float* C  = (const float*)d_in[8];
    const float* D  = (const float*)d_in[9];
    const float* c1 = (const float*)d_in[10];
    const float* c2 = (const float*)d_in[11];

    float* out  = (float*)d_out;
    float* xout = out;          // n
    float* Pf   = out + n;      // n*n fp32: Pk, becomes P_out in place

    // 8 bf16 NxN slots + Tf fp32 (2 slots) + small fp32 vectors  (~84 MB)
    u16* wsu = (u16*)d_ws;
    u16* S0 = wsu + 0 * NNE;  // Delta_h -> E_h
    u16* S1 = wsu + 1 * NNE;  // Pk_h    -> X (odd)  [final X]
    u16* S2 = wsu + 2 * NNE;  // T_h     -> X (even) -> H_l
    u16* S3 = wsu + 3 * NNE;  // T_l     -> H_h
    u16* S4 = wsu + 4 * NNE;  // G_h
    u16* S5 = wsu + 5 * NNE;  // G_l
    u16* S6 = wsu + 6 * NNE;  // Py_h
    u16* S7 = wsu + 7 * NNE;  // Py_l
    float* Tf = (float*)(wsu + 8 * NNE);   // fp32 T (slots 8-9)
    float* vecs = (float*)(wsu + 10 * NNE);
    float* w2   = vecs + 0 * n;
    float* xp   = vecs + 1 * n;
    float* rr   = vecs + 2 * n;
    float* va   = vecs + 3 * n;
    float* vb   = vecs + 4 * n;
    float* z0   = vecs + 5 * n;
    float* z1   = vecs + 6 * n;
    float* rho  = vecs + 7 * n;
    float* scal = vecs + 8 * n;

    dim3 blk256(256), blk512(512);
    dim3 gg(16, 16);            // 128x128 tiles -> 256 blocks (1/CU)

    // Pf = P + Q (+ bf16 hi) ; Delta = C - I (bf16 hi)
    fuse_pk<<<4096, blk256, 0, stream>>>(P, Q, Pf, S1);
    conv_delta<<<4096, blk256, 0, stream>>>(C, S0);

    // xp = A x + B u + c1 ; rr = (y - c2) - (C xp + D u)
    matvec_dual_f32<<<512, blk256, 0, stream>>>(A, x, B, u, c1, xp, 1.0f, n);
    vec_sub<<<8, blk256, 0, stream>>>(y, c2, w2, n);
    matvec_dual_f32<<<512, blk256, 0, stream>>>(C, xp, D, u, w2, rr, -1.0f, n);

    // T = Pk + TN(Delta_h, Pk_h)  -> Tf (fp32) + Th(S2)/Tl(S3)
    mfma_gemm<1, 1, 1, 1><<<gg, blk512, 0, stream>>>(S0, S1, nullptr, nullptr, 1,
                                                     Pf, nullptr, Tf, S2, S3);
    // Py = Tf + R + TN(T_h, Delta_h) -> Py_h(S6)/Py_l(S7)
    mfma_gemm<4, 1, 1, 0><<<gg, blk512, 0, stream>>>(S2, S0, nullptr, nullptr, 1,
                                                     Tf, R, nullptr, S6, S7);
    // G = T^T -> S4/S5
    transpose_pair<<<dim3(64, 64), blk256, 0, stream>>>(S2, S3, S4, S5);

    // power iteration for lambda_max(Py) -> alpha = 2/(1.3*lam)
    vec_fill<<<8, blk256, 0, stream>>>(va, 1.0f, n);
    float* pa = va; float* pb = vb;
    for (int i = 0; i < 7; ++i) {
        matvec_hl<<<512, blk256, 0, stream>>>(S6, nullptr, pa, nullptr, pb, 1.0f, n);
        float* tmp = pa; pa = pb; pb = tmp;
    }
    normsq<<<1, blk256, 0, stream>>>(pa, scal + 0, n);
    matvec_hl<<<512, blk256, 0, stream>>>(S6, nullptr, pa, nullptr, pb, 1.0f, n);
    normsq<<<1, blk256, 0, stream>>>(pb, scal + 1, n);
    alpha_k<<<1, 1, 0, stream>>>(scal + 0, scal + 1, scal + 2);

    // X1 = alpha*(2I - alpha*Py), elementwise -> S2 (T_h dead after G/Py)
    ns_init<<<4096, blk256, 0, stream>>>(S6, S7, scal + 2, S2);

    // 3 cheap NS iterations (hi-only): X: S2 -> S1 -> S2 -> S1
    u16* ch = S2; u16* oh = S1;
    for (int it = 0; it < 3; ++it) {
        mfma_gemm<3, 1, 0, 0><<<gg, blk512, 0, stream>>>(ch, S6, nullptr, nullptr, 1,
                                                         nullptr, nullptr, nullptr, S0, nullptr); // E = 2I - X Py
        mfma_gemm<0, 1, 0, 0><<<gg, blk512, 0, stream>>>(S0, ch, nullptr, nullptr, 1,
                                                         nullptr, nullptr, nullptr, oh, nullptr); // Xn = E X
        u16* tmp = ch; ch = oh; oh = tmp;
    }
    // final X = S1 (hi-only)

    // H = TN(G_h, X) + TN(G_l, X) -> H_h(S3)/H_l(S2)
    mfma_gemm<0, 1, 1, 0><<<gg, blk512, 0, stream>>>(S4, S1, S5, S1, 2,
                                                     nullptr, nullptr, nullptr, S3, S2);
    // P_out = Pf - [TN(H_h, G_h) + TN(H_l, G_h)] -> Pf in place
    mfma_gemm<2, 0, 0, 1><<<gg, blk512, 0, stream>>>(S3, S4, S2, S4, 2,
                                                     Pf, nullptr, Pf, nullptr, nullptr);

    // z = Py^{-1} rr by X-preconditioned iterative refinement (3 steps)
    matvec_hl<<<512, blk256, 0, stream>>>(S1, nullptr, rr, nullptr, z0, 1.0f, n);  // z0 = X r
    matvec_hl<<<512, blk256, 0, stream>>>(S6, S7, z0, rr, rho, -1.0f, n);          // rho = r - Py z0
    matvec_hl<<<512, blk256, 0, stream>>>(S1, nullptr, rho, z0, z1, 1.0f, n);      // z1 = z0 + X rho
    matvec_hl<<<512, blk256, 0, stream>>>(S6, S7, z1, rr, rho, -1.0f, n);          // rho = r - Py z1
    matvec_hl<<<512, blk256, 0, stream>>>(S1, nullptr, rho, z1, z0, 1.0f, n);      // z2 = z1 + X rho
    matvec_hl<<<512, blk256, 0, stream>>>(S6, S7, z0, rr, rho, -1.0f, n);          // rho = r - Py z2
    matvec_hl<<<512, blk256, 0, stream>>>(S1, nullptr, rho, z0, z1, 1.0f, n);      // z3 = z2 + X rho
    // x_out = xp + G z3
    matvec_hl<<<512, blk256, 0, stream>>>(S4, S5, z1, xp, xout, 1.0f, n);
}

// Round 9
// 394.967 us; speedup vs baseline: 1.6553x; 1.0609x over previous
//
#include <hip/hip_runtime.h>
#include <math.h>

// ---------------------------------------------------------------------------
// UKF(2048) == linear Kalman update (affine model => sigma machinery collapses).
// With C = I + D (||D||~0.02):
//   xp = A x + B u + c1 ; Pk = P + Q (fp32 Pf)
//   T  = Pk + D Pk ; Py = T + T D^T + R ; G = T^T
//   X ~= Py^{-1}: X1 = a(2I - a Py) analytic, then 3 hi-only NS GEMM iters
//   H = G X ; P_out = Pk - H G^T
//   z = Py^{-1} r via X-precond refinement (matvecs) ; x_out = xp + G z
// GEMM: TN MFMA ( TN(A,B)[m][n] = sum_k A[m][k]*B[n][k] ), 128x128 block,
// 256 blocks (1/CU), BK=64, 8 waves = 2x2 spatial x 2 K-split (r8 layout).
// NEW pipeline: depth-3-in-4-buffers, ONE barrier per tile, stage issued
// BEFORE compute (writes buffer (t+3)%4 != t%4 being read -> no mid barrier).
// Counted vmcnt(8) steady state, 8/4/0 tail.
// ---------------------------------------------------------------------------

typedef unsigned short u16;
typedef unsigned int u32;
typedef __attribute__((ext_vector_type(8))) short bf16x8;
typedef __attribute__((ext_vector_type(4))) float f32x4;

#define GN 2048
#define NNE ((size_t)GN * (size_t)GN)

#define WAITVM(N) asm volatile("s_waitcnt vmcnt(" #N ")" ::: "memory")
#define WAITLG()  asm volatile("s_waitcnt lgkmcnt(0)" ::: "memory")
#define BAR()     __builtin_amdgcn_s_barrier()

__device__ __forceinline__ u16 f2bf(float f) {
    union { float f; u32 u; } x; x.f = f;
    u32 r = x.u + 0x7fffu + ((x.u >> 16) & 1u);   // RNE
    return (u16)(r >> 16);
}
__device__ __forceinline__ float bf2f(u16 b) {
    union { u32 u; float f; } x; x.u = ((u32)b) << 16;
    return x.f;
}

__device__ __forceinline__ void gload16(const u16* g, u16* l) {
    __builtin_amdgcn_global_load_lds((const __attribute__((address_space(1))) u32*)g,
                                     (__attribute__((address_space(3))) u32*)l, 16, 0, 0);
}

// ---------------- elementwise / conversion ----------------

// Pf = P + Q (fp32), Pkh = bf16 hi of Pf
__global__ void fuse_pk(const float* __restrict__ P, const float* __restrict__ Q,
                        float* __restrict__ Pf, u16* __restrict__ Ph)
{
    size_t i = (size_t)blockIdx.x * 256 + threadIdx.x;   // over NNE/4
    float4 p = ((const float4*)P)[i];
    float4 q = ((const float4*)Q)[i];
    float s[4] = {p.x + q.x, p.y + q.y, p.z + q.z, p.w + q.w};
    ((float4*)Pf)[i] = make_float4(s[0], s[1], s[2], s[3]);
    ushort4 h;
    u16* hp = (u16*)&h;
#pragma unroll
    for (int e = 0; e < 4; ++e) hp[e] = f2bf(s[e]);
    ((ushort4*)Ph)[i] = h;
}

// Dh = bf16(C - I)
__global__ void conv_delta(const float* __restrict__ C, u16* __restrict__ Dh)
{
    size_t i = (size_t)blockIdx.x * 256 + threadIdx.x;   // over NNE/4
    size_t base = i * 4;
    u32 row = (u32)(base >> 11);
    u32 col0 = (u32)(base & (GN - 1));
    float4 p = ((const float4*)C)[i];
    float s[4] = {p.x, p.y, p.z, p.w};
    ushort4 h;
    u16* hp = (u16*)&h;
#pragma unroll
    for (int e = 0; e < 4; ++e)
        hp[e] = f2bf(s[e] - ((row == col0 + e) ? 1.0f : 0.0f));
    ((ushort4*)Dh)[i] = h;
}

__global__ void transpose_pair(const u16* __restrict__ Sh, const u16* __restrict__ Sl,
                               u16* __restrict__ Dh, u16* __restrict__ Dl)
{
    __shared__ u16 th[32][33];
    __shared__ u16 tl[32][33];
    int bi = blockIdx.y * 32, bj = blockIdx.x * 32;
    int r = threadIdx.x >> 5, c = threadIdx.x & 31;
    for (int rr = r; rr < 32; rr += 8) {
        th[rr][c] = Sh[(size_t)(bi + rr) * GN + bj + c];
        tl[rr][c] = Sl[(size_t)(bi + rr) * GN + bj + c];
    }
    __syncthreads();
    for (int rr = r; rr < 32; rr += 8) {
        Dh[(size_t)(bj + rr) * GN + bi + c] = th[c][rr];
        Dl[(size_t)(bj + rr) * GN + bi + c] = tl[c][rr];
    }
}

// X1 = a*(2I - a*Py) : first Newton-Schulz step is elementwise for X0 = a*I
__global__ void ns_init(const u16* __restrict__ Pyh, const u16* __restrict__ Pyl,
                        const float* __restrict__ alphap, u16* __restrict__ X)
{
    float a = alphap[0];
    size_t i4 = (size_t)blockIdx.x * 256 + threadIdx.x;   // over NNE/4
    size_t base = i4 * 4;
    u32 row = (u32)(base >> 11);
    u32 col0 = (u32)(base & (GN - 1));
    ushort4 h = ((const ushort4*)Pyh)[i4];
    ushort4 lo = ((const ushort4*)Pyl)[i4];
    u16 hv[4] = {h.x, h.y, h.z, h.w};
    u16 lv[4] = {lo.x, lo.y, lo.z, lo.w};
    ushort4 o;
    u16* op = (u16*)&o;
#pragma unroll
    for (int e = 0; e < 4; ++e) {
        float py = bf2f(hv[e]) + bf2f(lv[e]);
        float v = a * (((row == col0 + e) ? 2.0f : 0.0f) - a * py);
        op[e] = f2bf(v);
    }
    ((ushort4*)X)[i4] = o;
}

// ---------------- vector kernels ----------------

// out[row] = addv[row] + sign*( dot(A[row,:],v1) + dot(B[row,:],v2) )
__global__ void matvec_dual_f32(const float* __restrict__ A, const float* __restrict__ v1,
                                const float* __restrict__ B, const float* __restrict__ v2,
                                const float* __restrict__ addv, float* __restrict__ out,
                                float sign, int n)
{
    int wid = threadIdx.x >> 6, lane = threadIdx.x & 63;
    int row = blockIdx.x * 4 + wid;
    if (row >= n) return;
    const float* ar = A + (size_t)row * n;
    const float* br = B + (size_t)row * n;
    float s = 0.f;
    for (int j = lane; j < n; j += 64) s += ar[j] * v1[j] + br[j] * v2[j];
#pragma unroll
    for (int off = 32; off > 0; off >>= 1) s += __shfl_down(s, off);
    if (lane == 0) out[row] = addv[row] + sign * s;
}

// out[row] = (addv ? addv[row] : 0) + sign * dot((hi+lo)[row,:], v)
__global__ void matvec_hl(const u16* __restrict__ Mh, const u16* __restrict__ Ml,
                          const float* __restrict__ v, const float* __restrict__ addv,
                          float* __restrict__ out, float sign, int n)
{
    int wid = threadIdx.x >> 6, lane = threadIdx.x & 63;
    int row = blockIdx.x * 4 + wid;
    if (row >= n) return;
    const u16* hr = Mh + (size_t)row * n;
    const u16* lr = Ml ? Ml + (size_t)row * n : (const u16*)0;
    float s = 0.f;
    for (int j = lane * 8; j < n; j += 512) {
        uint4 hb = *(const uint4*)&hr[j];
        float4 v0 = *(const float4*)&v[j];
        float4 v1 = *(const float4*)&v[j + 4];
        u32 hw[4] = {hb.x, hb.y, hb.z, hb.w};
        float m[8];
#pragma unroll
        for (int e = 0; e < 4; ++e) {
            m[2 * e]     = bf2f((u16)(hw[e] & 0xffffu));
            m[2 * e + 1] = bf2f((u16)(hw[e] >> 16));
        }
        if (lr) {
            uint4 lb = *(const uint4*)&lr[j];
            u32 lw[4] = {lb.x, lb.y, lb.z, lb.w};
#pragma unroll
            for (int e = 0; e < 4; ++e) {
                m[2 * e]     += bf2f((u16)(lw[e] & 0xffffu));
                m[2 * e + 1] += bf2f((u16)(lw[e] >> 16));
            }
        }
        s += m[0] * v0.x + m[1] * v0.y + m[2] * v0.z + m[3] * v0.w
           + m[4] * v1.x + m[5] * v1.y + m[6] * v1.z + m[7] * v1.w;
    }
#pragma unroll
    for (int off = 32; off > 0; off >>= 1) s += __shfl_down(s, off);
    if (lane == 0) out[row] = (addv ? addv[row] : 0.f) + sign * s;
}

__global__ void vec_sub(const float* __restrict__ a, const float* __restrict__ b,
                        float* __restrict__ o, int n)
{
    int i = blockIdx.x * 256 + threadIdx.x;
    if (i < n) o[i] = a[i] - b[i];
}

__global__ void vec_fill(float* __restrict__ o, float val, int n)
{
    int i = blockIdx.x * 256 + threadIdx.x;
    if (i < n) o[i] = val;
}

__global__ void normsq(const float* __restrict__ v, float* __restrict__ out, int n)
{
    __shared__ float sm[256];
    float s = 0.f;
    for (int i = threadIdx.x; i < n; i += 256) { float x = v[i]; s += x * x; }
    sm[threadIdx.x] = s;
    __syncthreads();
    for (int w = 128; w > 0; w >>= 1) {
        if (threadIdx.x < w) sm[threadIdx.x] += sm[threadIdx.x + w];
        __syncthreads();
    }
    if (threadIdx.x == 0) out[0] = sm[0];
}

__global__ void alpha_k(const float* __restrict__ ns9, const float* __restrict__ ns10,
                        float* __restrict__ alpha)
{
    float lam = sqrtf(ns10[0] / ns9[0]);
    alpha[0] = 2.0f / (1.3f * lam);
}

// --- MFMA TN-GEMM: 128x128 block, 8 waves = 2x2 spatial x 2 K-split ---------
// Pipeline: depth-3-in-4-buffers, 1 barrier/tile, stage-before-compute.
// O = op(MODE){ sum_s A_s B_s^T } ; MODE 0:S 1:S+Dm 2:Dm-S 3:2I-S 4:S+Dm+Dm2
template <int MODE, int WHI, int WLO, int WF32>
__global__ __launch_bounds__(512, 2) void mfma_gemm(
    const u16* A0, const u16* B0, const u16* A1, const u16* B1, int nseg,
    const float* Dm, const float* Dm2, float* Of, u16* Ohi, u16* Olo)
{
    __shared__ __align__(16) u16 ldsbuf[65536];     // 128 KB: A[4] then B[4]
    u16* As0 = ldsbuf;          u16* Bs0 = ldsbuf + 32768;
    u16* As1 = ldsbuf + 8192;   u16* Bs1 = ldsbuf + 40960;
    u16* As2 = ldsbuf + 16384;  u16* Bs2 = ldsbuf + 49152;
    u16* As3 = ldsbuf + 24576;  u16* Bs3 = ldsbuf + 57344;

    const int t = threadIdx.x;
    const int wid = t >> 6, l = t & 63;
    const int wk = wid >> 2;                // K-half (0: k 0-31, 1: k 32-63)
    const int wr = (wid >> 1) & 1;          // 2x2 spatial grid of 64x64 tiles
    const int wc = wid & 1;
    const int m0 = blockIdx.y * 128, n0 = blockIdx.x * 128;

    f32x4 acc[4][4] = {};

    // staging: wave w stages A rows [w*16,w*16+16) and B rows [w*16,w*16+16);
    // 2 gload16 each (8 rows per instr). LDS linear; XOR swizzle via permuted
    // GLOBAL source column: phys slot(row, sl) = global col sl^(row&7).
    const int srow = l >> 3;                            // 0..7
    const int scol = (((l & 7) ^ srow) << 3);           // source col (elems)
    const size_t ago = (size_t)(m0 + wid * 16 + srow) * GN + scol;
    const size_t bgo = (size_t)(n0 + wid * 16 + srow) * GN + scol;
    const int ldsW = wid * 1024;

    // read side: logical k-slot (wk*4 + l>>4) XOR (row&7); K-half by wk
    const int lrow = l & 15;
    const int lq = l >> 4;
    const int lb = l & 7;
    int aoff[4], boff[4];
#pragma unroll
    for (int mi = 0; mi < 4; ++mi) {
        int r = wr * 64 + mi * 16 + lrow;
        aoff[mi] = r * 64 + (((wk * 4 + lq) ^ lb) << 3);
    }
#pragma unroll
    for (int ni = 0; ni < 4; ++ni) {
        int r = wc * 64 + ni * 16 + lrow;
        boff[ni] = r * 64 + (((wk * 4 + lq) ^ lb) << 3);
    }

    const int nt = nseg * 32;   // BK=64 -> 32 tiles/segment; nt in {32,64}

    auto stage = [&](int tile, u16* Ad, u16* Bd) {   // 4 global_load_lds/wave
        int sn = tile >> 5;
        size_t kn = (size_t)(tile & 31) << 6;
        const u16* Ap = (sn == 0) ? A0 : A1;
        const u16* Bp = (sn == 0) ? B0 : B1;
        const u16* gA = Ap + ago + kn;
        const u16* gB = Bp + bgo + kn;
        gload16(gA, Ad + ldsW);
        gload16(gA + (size_t)8 * GN, Ad + ldsW + 512);
        gload16(gB, Bd + ldsW);
        gload16(gB + (size_t)8 * GN, Bd + ldsW + 512);
    };
    auto compute = [&](const u16* Asrc, const u16* Bsrc) {   // K=32 half
        __builtin_amdgcn_s_setprio(1);
        bf16x8 af[4], bq[4];
#pragma unroll
        for (int mi = 0; mi < 4; ++mi)
            af[mi] = *(const bf16x8*)&Asrc[aoff[mi]];
#pragma unroll
        for (int ni = 0; ni < 4; ++ni)
            bq[ni] = *(const bf16x8*)&Bsrc[boff[ni]];
#pragma unroll
        for (int mi = 0; mi < 4; ++mi)
#pragma unroll
            for (int ni = 0; ni < 4; ++ni)
                acc[mi][ni] = __builtin_amdgcn_mfma_f32_16x16x32_bf16(
                    af[mi], bq[ni], acc[mi][ni], 0, 0, 0);
        __builtin_amdgcn_s_setprio(0);
    };

    // ---- depth-3-in-4-buffers pipeline, ONE barrier per tile ----
    // Invariant entering tile t's slot: tile t ready, tiles t+1,t+2 in
    // flight (8 loads). Slot: stage(t+3) [disjoint buffer], compute(t),
    // WAITLG (drain own ds_reads), WAITVM(8) (tile t+1 landed), BAR.
    stage(0, As0, Bs0);
    stage(1, As1, Bs1);
    stage(2, As2, Bs2);
    WAITVM(8); BAR();                       // tile 0 ready; 1,2 in flight
    for (int tt = 0; tt + 4 < nt; tt += 4) {
        stage(tt + 3, As3, Bs3); compute(As0, Bs0);
        WAITLG(); WAITVM(8); BAR();
        stage(tt + 4, As0, Bs0); compute(As1, Bs1);
        WAITLG(); WAITVM(8); BAR();
        stage(tt + 5, As1, Bs1); compute(As2, Bs2);
        WAITLG(); WAITVM(8); BAR();
        stage(tt + 6, As2, Bs2); compute(As3, Bs3);
        WAITLG(); WAITVM(8); BAR();
    }
    // epilogue: tt == nt-4; tiles nt-4..nt-1; only nt-1 still to stage
    stage(nt - 1, As3, Bs3); compute(As0, Bs0);
    WAITLG(); WAITVM(8); BAR();             // tile nt-3 ready
    compute(As1, Bs1);
    WAITLG(); WAITVM(4); BAR();             // tile nt-2 ready
    compute(As2, Bs2);
    WAITLG(); WAITVM(0); BAR();             // tile nt-1 ready
    compute(As3, Bs3);

    // ---- cross-K reduction: wk=1 waves dump acc to padded LDS, wk=0 add ----
    // region per (wr,wc): 64x68 f32 (stride 68 -> 2-way bank conflicts only)
    float* red = (float*)ldsbuf;
    const int reg = (wr * 2 + wc) * 4352;
    WAITLG(); BAR();                       // all LDS tile reads done; safe reuse
    if (wk == 1) {
#pragma unroll
        for (int mi = 0; mi < 4; ++mi)
#pragma unroll
            for (int ni = 0; ni < 4; ++ni)
#pragma unroll
                for (int r = 0; r < 4; ++r)
                    red[reg + (mi * 16 + lq * 4 + r) * 68 + ni * 16 + lrow] =
                        acc[mi][ni][r];
    }
    WAITLG(); BAR();
    if (wk == 0) {
#pragma unroll
        for (int mi = 0; mi < 4; ++mi)
#pragma unroll
            for (int ni = 0; ni < 4; ++ni)
#pragma unroll
                for (int r = 0; r < 4; ++r)
                    acc[mi][ni][r] +=
                        red[reg + (mi * 16 + lq * 4 + r) * 68 + ni * 16 + lrow];

        // epilogue (wk=0 waves only): C/D frag col = l&15, row = lq*4 + r
#pragma unroll
        for (int mi = 0; mi < 4; ++mi) {
#pragma unroll
            for (int r = 0; r < 4; ++r) {
                int gm = m0 + wr * 64 + mi * 16 + lq * 4 + r;
                size_t rowo = (size_t)gm * GN;
#pragma unroll
                for (int ni = 0; ni < 4; ++ni) {
                    int gn = n0 + wc * 64 + ni * 16 + lrow;
                    float v = acc[mi][ni][r];
                    if (MODE == 1) v = v + Dm[rowo + gn];
                    else if (MODE == 2) v = Dm[rowo + gn] - v;
                    else if (MODE == 3) v = ((gm == gn) ? 2.0f : 0.0f) - v;
                    else if (MODE == 4) v = v + Dm[rowo + gn] + Dm2[rowo + gn];
                    if (WF32) Of[rowo + gn] = v;
                    if (WHI) {
                        u16 h = f2bf(v);
                        Ohi[rowo + gn] = h;
                        if (WLO) Olo[rowo + gn] = f2bf(v - bf2f(h));
                    }
                }
            }
        }
    }
}

// ---------------- host ----------------

extern "C" void kernel_launch(void* const* d_in, const int* in_sizes, int n_in,
                              void* d_out, int out_size, void* d_ws, size_t ws_size,
                              hipStream_t stream)
{
    const int n = GN;
    const float* x  = (const float*)d_in[0];
    const float* y  = (const float*)d_in[1];
    const float* u  = (const float*)d_in[2];
    const float* P  = (const float*)d_in[3];
    const float* Q  = (const float*)d_in[4];
    const float* R  = (const float*)d_in[5];
    const float* A  = (const float*)d_in[6];
    const float* B  = (const float*)d_in[7];
    const float* C  = (const float*)d_in[8];
    const float* D  = (const float*)d_in[9];
    const float* c1 = (const float*)d_in[10];
    const float* c2 = (const float*)d_in[11];

    float* out  = (float*)d_out;
    float* xout = out;          // n
    float* Pf   = out + n;      // n*n fp32: Pk, becomes P_out in place

    // 8 bf16 NxN slots + Tf fp32 (2 slots) + small fp32 vectors  (~84 MB)
    u16* wsu = (u16*)d_ws;
    u16* S0 = wsu + 0 * NNE;  // Delta_h -> E_h
    u16* S1 = wsu + 1 * NNE;  // Pk_h    -> X (odd)  [final X]
    u16* S2 = wsu + 2 * NNE;  // T_h     -> X (even) -> H_l
    u16* S3 = wsu + 3 * NNE;  // T_l     -> H_h
    u16* S4 = wsu + 4 * NNE;  // G_h
    u16* S5 = wsu + 5 * NNE;  // G_l
    u16* S6 = wsu + 6 * NNE;  // Py_h
    u16* S7 = wsu + 7 * NNE;  // Py_l
    float* Tf = (float*)(wsu + 8 * NNE);   // fp32 T (slots 8-9)
    float* vecs = (float*)(wsu + 10 * NNE);
    float* w2   = vecs + 0 * n;
    float* xp   = vecs + 1 * n;
    float* rr   = vecs + 2 * n;
    float* va   = vecs + 3 * n;
    float* vb   = vecs + 4 * n;
    float* z0   = vecs + 5 * n;
    float* z1   = vecs + 6 * n;
    float* rho  = vecs + 7 * n;
    float* scal = vecs + 8 * n;

    dim3 blk256(256), blk512(512);
    dim3 gg(16, 16);            // 128x128 tiles -> 256 blocks (1/CU)

    // Pf = P + Q (+ bf16 hi) ; Delta = C - I (bf16 hi)
    fuse_pk<<<4096, blk256, 0, stream>>>(P, Q, Pf, S1);
    conv_delta<<<4096, blk256, 0, stream>>>(C, S0);

    // xp = A x + B u + c1 ; rr = (y - c2) - (C xp + D u)
    matvec_dual_f32<<<512, blk256, 0, stream>>>(A, x, B, u, c1, xp, 1.0f, n);
    vec_sub<<<8, blk256, 0, stream>>>(y, c2, w2, n);
    matvec_dual_f32<<<512, blk256, 0, stream>>>(C, xp, D, u, w2, rr, -1.0f, n);

    // T = Pk + TN(Delta_h, Pk_h)  -> Tf (fp32) + Th(S2)/Tl(S3)
    mfma_gemm<1, 1, 1, 1><<<gg, blk512, 0, stream>>>(S0, S1, nullptr, nullptr, 1,
                                                     Pf, nullptr, Tf, S2, S3);
    // Py = Tf + R + TN(T_h, Delta_h) -> Py_h(S6)/Py_l(S7)
    mfma_gemm<4, 1, 1, 0><<<gg, blk512, 0, stream>>>(S2, S0, nullptr, nullptr, 1,
                                                     Tf, R, nullptr, S6, S7);
    // G = T^T -> S4/S5
    transpose_pair<<<dim3(64, 64), blk256, 0, stream>>>(S2, S3, S4, S5);

    // power iteration for lambda_max(Py) -> alpha = 2/(1.3*lam)
    vec_fill<<<8, blk256, 0, stream>>>(va, 1.0f, n);
    float* pa = va; float* pb = vb;
    for (int i = 0; i < 7; ++i) {
        matvec_hl<<<512, blk256, 0, stream>>>(S6, nullptr, pa, nullptr, pb, 1.0f, n);
        float* tmp = pa; pa = pb; pb = tmp;
    }
    normsq<<<1, blk256, 0, stream>>>(pa, scal + 0, n);
    matvec_hl<<<512, blk256, 0, stream>>>(S6, nullptr, pa, nullptr, pb, 1.0f, n);
    normsq<<<1, blk256, 0, stream>>>(pb, scal + 1, n);
    alpha_k<<<1, 1, 0, stream>>>(scal + 0, scal + 1, scal + 2);

    // X1 = alpha*(2I - alpha*Py), elementwise -> S2 (T_h dead after G/Py)
    ns_init<<<4096, blk256, 0, stream>>>(S6, S7, scal + 2, S2);

    // 3 cheap NS iterations (hi-only): X: S2 -> S1 -> S2 -> S1
    u16* ch = S2; u16* oh = S1;
    for (int it = 0; it < 3; ++it) {
        mfma_gemm<3, 1, 0, 0><<<gg, blk512, 0, stream>>>(ch, S6, nullptr, nullptr, 1,
                                                         nullptr, nullptr, nullptr, S0, nullptr); // E = 2I - X Py
        mfma_gemm<0, 1, 0, 0><<<gg, blk512, 0, stream>>>(S0, ch, nullptr, nullptr, 1,
                                                         nullptr, nullptr, nullptr, oh, nullptr); // Xn = E X
        u16* tmp = ch; ch = oh; oh = tmp;
    }
    // final X = S1 (hi-only)

    // H = TN(G_h, X) + TN(G_l, X) -> H_h(S3)/H_l(S2)
    mfma_gemm<0, 1, 1, 0><<<gg, blk512, 0, stream>>>(S4, S1, S5, S1, 2,
                                                     nullptr, nullptr, nullptr, S3, S2);
    // P_out = Pf - [TN(H_h, G_h) + TN(H_l, G_h)] -> Pf in place
    mfma_gemm<2, 0, 0, 1><<<gg, blk512, 0, stream>>>(S3, S4, S2, S4, 2,
                                                     Pf, nullptr, Pf, nullptr, nullptr);

    // z = Py^{-1} rr by X-preconditioned iterative refinement (2 steps)
    matvec_hl<<<512, blk256, 0, stream>>>(S1, nullptr, rr, nullptr, z0, 1.0f, n);  // z0 = X r
    matvec_hl<<<512, blk256, 0, stream>>>(S6, S7, z0, rr, rho, -1.0f, n);          // rho = r - Py z0
    matvec_hl<<<512, blk256, 0, stream>>>(S1, nullptr, rho, z0, z1, 1.0f, n);      // z1 = z0 + X rho
    matvec_hl<<<512, blk256, 0, stream>>>(S6, S7, z1, rr, rho, -1.0f, n);          // rho = r - Py z1
    matvec_hl<<<512, blk256, 0, stream>>>(S1, nullptr, rho, z1, z0, 1.0f, n);      // z2 = z1 + X rho
    // x_out = xp + G z2
    matvec_hl<<<512, blk256, 0, stream>>>(S4, S5, z0, xp, xout, 1.0f, n);
}